// Round 5
// baseline (18330.267 us; speedup 1.0000x reference)
//
#include <hip/hip_runtime.h>
#include <stdint.h>

// ---------------------------------------------------------------------------
// LSTMSupertaggingModel: segment-mean-pool -> BiLSTM(H=384) -> Linear(C=425)
// B=64, S=512, D=768, W=256, H=384, C=425
//
// R5: recurrence with ZERO inter-workgroup communication.
//   Insight: batch doesn't couple in the recurrence; only the h-dim does.
//   8 wgs x 1024 threads, wg = (dir, btile of 16 batch rows). Full Whh for
//   the dir is register-resident across the wg's 16 waves (288 VGPR/lane of
//   B-frags; RF=2048/SIMD -> 4 waves/SIMD fits). All h(t-1) exchange and the
//   cross-gate gather run through LDS (62 KB static): per step
//     A-frags(ds_read) -> 72 MFMA -> gates to LDS (2 j-phases, reused
//     region) -> cell -> h to LDS + deferred global store.
//   No atomics, no fences, no tags -> the 2-3 us/step fabric floor of
//   R1-R4 is gone; step is all on-CU (~1 us predicted).
// ---------------------------------------------------------------------------

typedef __attribute__((ext_vector_type(8))) short short8;
typedef __attribute__((ext_vector_type(4))) float f32x4;

static constexpr int Bn = 64, Sn = 512, Dn = 768, Wn = 256, Hn = 384, Cn = 425;
static constexpr int G4H = 4 * Hn;          // 1536

__device__ __forceinline__ unsigned short f2bf(float f) {
  unsigned int u = __float_as_uint(f);
  u += 0x7FFFu + ((u >> 16) & 1u);          // round-to-nearest-even
  return (unsigned short)(u >> 16);
}
__device__ __forceinline__ float bf2f(unsigned short h) {
  return __uint_as_float(((unsigned int)h) << 16);
}
__device__ __forceinline__ float sigm(float x)  { return 1.f / (1.f + __expf(-x)); }
__device__ __forceinline__ float tanhft(float x){ return 1.f - 2.f / (__expf(2.f * x) + 1.f); }

// async global->LDS, 16B per lane; LDS dest = wave-uniform base + lane*16
#define GLL16(gp, lp) __builtin_amdgcn_global_load_lds( \
  (const __attribute__((address_space(1))) unsigned int*)(gp), \
  (__attribute__((address_space(3))) unsigned int*)(lp), 16, 0, 0)

// ---------------------------------------------------------------------------
__global__ void scan_starts(const int* __restrict__ counts, int* __restrict__ starts) {
  int b = blockIdx.x, j = threadIdx.x;      // 64 blocks x 256 threads
  __shared__ int sm[256];
  int c = counts[b * Wn + j];
  sm[j] = c;
  __syncthreads();
  for (int off = 1; off < 256; off <<= 1) {
    int v = (j >= off) ? sm[j - off] : 0;
    __syncthreads();
    sm[j] += v;
    __syncthreads();
  }
  starts[b * Wn + j] = sm[j] - c;           // exclusive
}

// ---------------------------------------------------------------------------
__global__ void prep_cast(const float* __restrict__ Wih_f, const float* __restrict__ Wih_b,
                          const float* __restrict__ Whh_f, const float* __restrict__ Whh_b,
                          const float* __restrict__ Wlin,
                          const float* __restrict__ bih_f, const float* __restrict__ bhh_f,
                          const float* __restrict__ bih_b, const float* __restrict__ bhh_b,
                          unsigned short* __restrict__ wih, unsigned short* __restrict__ whh,
                          unsigned short* __restrict__ wlin, float* __restrict__ biasc) {
  int i = blockIdx.x * 256 + threadIdx.x;
  const int T0 = 3072 * 768;                // Wih both dirs
  const int T1 = 2 * 1536 * 384;            // Whh both dirs
  const int T2 = Cn * 768;                  // Wlin
  const int T3 = 3072;                      // bias
  if (i < T0) {
    int n = i / 768, k = i - n * 768;
    float v = (n < 1536) ? Wih_f[n * 768 + k] : Wih_b[(n - 1536) * 768 + k];
    wih[i] = f2bf(v);
  } else if (i < T0 + T1) {
    int j = i - T0;
    float v = (j < 1536 * 384) ? Whh_f[j] : Whh_b[j - 1536 * 384];
    whh[j] = f2bf(v);
  } else if (i < T0 + T1 + T2) {
    int j = i - T0 - T1;
    wlin[j] = f2bf(Wlin[j]);
  } else if (i < T0 + T1 + T2 + T3) {
    int n = i - T0 - T1 - T2;
    biasc[n] = (n < 1536) ? (bih_f[n] + bhh_f[n]) : (bih_b[n - 1536] + bhh_b[n - 1536]);
  }
}

// ---------------------------------------------------------------------------
// ragged segment mean: f0p[b*S+s][:] = s<W ? mean(f0[b, st..st+cnt)) : f0[b,s]
__global__ void pool_kernel(const float* __restrict__ f0, const int* __restrict__ counts,
                            const int* __restrict__ starts, unsigned short* __restrict__ f0p) {
  int idx = blockIdx.x * 256 + threadIdx.x;           // B*S*192 exact
  int dc = idx % 192;
  int rest = idx / 192;
  int s = rest & 511, b = rest >> 9;
  const float4* f4 = (const float4*)f0;
  float4 v;
  if (s < Wn) {
    int st = starts[b * Wn + s], cnt = counts[b * Wn + s];
    v = f4[(size_t)(b * Sn + st) * 192 + dc];
    if (cnt == 2) {
      float4 v2 = f4[(size_t)(b * Sn + st + 1) * 192 + dc];
      v.x = (v.x + v2.x) * 0.5f; v.y = (v.y + v2.y) * 0.5f;
      v.z = (v.z + v2.z) * 0.5f; v.w = (v.w + v2.w) * 0.5f;
    }
  } else {
    v = f4[(size_t)(b * Sn + s) * 192 + dc];
  }
  ushort4 o;
  o.x = f2bf(v.x); o.y = f2bf(v.y); o.z = f2bf(v.z); o.w = f2bf(v.w);
  ((ushort4*)f0p)[(size_t)(b * Sn + s) * 192 + dc] = o;
}

// ---------------------------------------------------------------------------
// xp GEMM: A = f0p [32768][768] bf16, B = wih [3072][768] bf16 (rows = gate)
// out: xp[d][t][b][1536] bf16,  value = A@B^T + biasc
__global__ void gemm_xp(const unsigned short* __restrict__ A, const unsigned short* __restrict__ Bw,
                        const float* __restrict__ biasc, unsigned short* __restrict__ xp) {
  __shared__ __align__(16) unsigned short As[128 * 32];
  __shared__ __align__(16) unsigned short Bs[128 * 32];
  int tid = threadIdx.x, w = tid >> 6, l = tid & 63, lr = l & 15, lq = l >> 4;
  int mBase = blockIdx.x * 128, nBase = blockIdx.y * 128;
  int mw = (w & 1) * 64, nw = (w >> 1) * 64;
  f32x4 acc[4][4];
#pragma unroll
  for (int mt = 0; mt < 4; ++mt)
#pragma unroll
    for (int nt = 0; nt < 4; ++nt) acc[mt][nt] = (f32x4){0.f, 0.f, 0.f, 0.f};

  for (int kb = 0; kb < 24; ++kb) {
    int k0 = kb * 32;
#pragma unroll
    for (int j = 0; j < 2; ++j) {
      int g = j * 256 + tid;
      int row = g >> 2, kc = (g & 3) * 8;
      GLL16(A + (size_t)(mBase + row) * 768 + k0 + kc, (char*)As + (j * 256 + w * 64) * 16);
      GLL16(Bw + (size_t)(nBase + row) * 768 + k0 + kc, (char*)Bs + (j * 256 + w * 64) * 16);
    }
    __syncthreads();
    short8 af[4], bfv[4];
#pragma unroll
    for (int mt = 0; mt < 4; ++mt) af[mt] = *(const short8*)&As[(mw + mt * 16 + lr) * 32 + lq * 8];
#pragma unroll
    for (int nt = 0; nt < 4; ++nt) bfv[nt] = *(const short8*)&Bs[(nw + nt * 16 + lr) * 32 + lq * 8];
#pragma unroll
    for (int mt = 0; mt < 4; ++mt)
#pragma unroll
      for (int nt = 0; nt < 4; ++nt)
        acc[mt][nt] = __builtin_amdgcn_mfma_f32_16x16x32_bf16(af[mt], bfv[nt], acc[mt][nt], 0, 0, 0);
    __syncthreads();
  }
  // epilogue: +bias, scatter to xp[d][t][b][g]
#pragma unroll
  for (int nt = 0; nt < 4; ++nt) {
    int n = nBase + nw + nt * 16 + lr;
    float bias = biasc[n];
    int d = (n >= 1536) ? 1 : 0;
    int gI = n - d * 1536;
#pragma unroll
    for (int mt = 0; mt < 4; ++mt) {
      int mrow = mBase + mw + mt * 16 + lq * 4;
#pragma unroll
      for (int r = 0; r < 4; ++r) {
        int m = mrow + r;
        int t = m & 511, b = m >> 9;
        xp[((size_t)((d * Sn + t) * Bn + b)) * 1536 + gI] = f2bf(acc[mt][nt][r] + bias);
      }
    }
  }
}

// ---------------------------------------------------------------------------
// Recurrence: 8 wgs x 1024 threads, wg = (dir, btile). No inter-wg comm.
// Wave wid: gate q=wid>>2, j-quarter jr=wid&3 -> n-slice of 96 (6 n-tiles),
// full k=384 (12 k-frags). B-frags register-resident: 72 x short8 = 288 VGPR.
// LDS: gates[16][776] f32 (one 192-j phase, reused) + hbuf[16][392] bf16.
__global__ void __launch_bounds__(1024, 1)
recur_kernel(const unsigned short* __restrict__ whh,   // [2][1536][384] bf16
             const unsigned short* __restrict__ xp,    // [2][512][64][1536] bf16
             unsigned short* __restrict__ h_all) {     // [64][512][768] bf16
  const int bid = blockIdx.x;               // 0..7
  const int dir = bid >> 2, btile = bid & 3;
  const int tid = threadIdx.x;
  const int wid = tid >> 6, l = tid & 63, lr = l & 15, lq = l >> 4;
  const int q = wid >> 2;                   // gate 0..3 (i,f,g,o)
  const int jr = wid & 3;                   // j-quarter (96 wide)
  const int nbase = q * 384 + jr * 96;      // this wave's n-row base in whh
  const int jph = (jr & 1) * 96;            // j' base within the phase buffer
  const int cb = tid & 15;                  // cell: batch row
  const int cj = tid >> 4;                  // cell: j-triple index 0..63

  __shared__ float gates[16 * 776];             // 49664 B, [b][q*192 + j']
  __shared__ unsigned short hbuf[16 * 392];     // 12544 B, [b][j] h(t-1)/h(t)

  // permanent B-frags: whh[dir][nbase + nt*16 + lr][kf*32 + lq*8 .. +8]
  short8 bfr[6][12];
#pragma unroll
  for (int nt = 0; nt < 6; ++nt)
#pragma unroll
    for (int kf = 0; kf < 12; ++kf)
      bfr[nt][kf] = *(const short8*)&whh[((size_t)dir * 1536 + nbase + nt * 16 + lr) * 384 + kf * 32 + lq * 8];

  // xp prefetch for step 0
  unsigned short pref[6][4];
  {
    int t0 = dir ? (Sn - 1) : 0;
    const unsigned short* xb = xp + ((size_t)((dir * Sn + t0) * Bn + btile * 16)) * 1536 + nbase + lr;
#pragma unroll
    for (int nt = 0; nt < 6; ++nt)
#pragma unroll
      for (int r = 0; r < 4; ++r)
        pref[nt][r] = xb[(size_t)(lq * 4 + r) * 1536 + nt * 16];
  }

  float cst[2][3] = {{0.f, 0.f, 0.f}, {0.f, 0.f, 0.f}};
  unsigned short hprev[2][3];               // deferred h_all stores
  int tprev = 0;

  for (int it = 0; it < Sn; ++it) {
    int t = dir ? (Sn - 1 - it) : it;

    // deferred h_all stores of step it-1 (drain cost folds into bar1 window)
    if (it > 0) {
      unsigned short* hb = h_all + ((size_t)(btile * 16 + cb) * Sn + tprev) * 768 + dir * Hn;
#pragma unroll
      for (int ph = 0; ph < 2; ++ph)
#pragma unroll
        for (int cc = 0; cc < 3; ++cc)
          hb[ph * 192 + cj * 3 + cc] = hprev[ph][cc];
    }

    // acc init from prefetched xp
    f32x4 acc[6];
#pragma unroll
    for (int nt = 0; nt < 6; ++nt)
#pragma unroll
      for (int r = 0; r < 4; ++r)
        acc[nt][r] = bf2f(pref[nt][r]);

    // issue next step's xp prefetch (latency hidden behind MFMA phase)
    if (it + 1 < Sn) {
      int t2 = dir ? (t - 1) : (t + 1);
      const unsigned short* xb = xp + ((size_t)((dir * Sn + t2) * Bn + btile * 16)) * 1536 + nbase + lr;
#pragma unroll
      for (int nt = 0; nt < 6; ++nt)
#pragma unroll
        for (int r = 0; r < 4; ++r)
          pref[nt][r] = xb[(size_t)(lq * 4 + r) * 1536 + nt * 16];
    }

    // recurrent MFMA: A = h(t-1) from hbuf, B = register-resident Whh slice
    if (it > 0) {
#pragma unroll
      for (int kf = 0; kf < 12; ++kf) {
        short8 a = *(const short8*)((const char*)hbuf + lr * 784 + kf * 64 + lq * 16);
#pragma unroll
        for (int nt = 0; nt < 6; ++nt)
          acc[nt] = __builtin_amdgcn_mfma_f32_16x16x32_bf16(a, bfr[nt][kf], acc[nt], 0, 0, 0);
      }
    }
    __syncthreads();                        // bar1: hbuf reads done wg-wide

    // phase-A gate writes (j < 192): waves jr 0,1
    if (jr < 2) {
#pragma unroll
      for (int nt = 0; nt < 6; ++nt)
#pragma unroll
        for (int r = 0; r < 4; ++r)
          gates[(lq * 4 + r) * 776 + q * 192 + jph + nt * 16 + lr] = acc[nt][r];
    }
    __syncthreads();                        // bar2: phase-A gates visible

#pragma unroll
    for (int ph = 0; ph < 2; ++ph) {
      // gather this phase's gate quadruples to registers
      float gv[3][4];
#pragma unroll
      for (int cc = 0; cc < 3; ++cc) {
        int jp = cj * 3 + cc;
#pragma unroll
        for (int qq = 0; qq < 4; ++qq)
          gv[cc][qq] = gates[cb * 776 + qq * 192 + jp];
      }
      __syncthreads();                      // gate reads done -> region reusable
      // phase-B waves overwrite the gate region during the ph==0 window
      if (ph == 0 && jr >= 2) {
#pragma unroll
        for (int nt = 0; nt < 6; ++nt)
#pragma unroll
          for (int r = 0; r < 4; ++r)
            gates[(lq * 4 + r) * 776 + q * 192 + jph + nt * 16 + lr] = acc[nt][r];
      }
      // cell: 3 h-values per lane for this phase
#pragma unroll
      for (int cc = 0; cc < 3; ++cc) {
        int j = ph * 192 + cj * 3 + cc;
        float iv = sigm(gv[cc][0]);
        float fv = sigm(gv[cc][1]);
        float gg = tanhft(gv[cc][2]);
        float ov = sigm(gv[cc][3]);
        float cf = fv * cst[ph][cc] + iv * gg;
        cst[ph][cc] = cf;
        float hv = ov * tanhft(cf);
        unsigned short hbv = f2bf(hv);
        hbuf[cb * 392 + j] = hbv;
        hprev[ph][cc] = hbv;                // global store deferred to next step
      }
      __syncthreads();                      // phase gates consumed / hbuf settled
    }
    tprev = t;
  }

  // final step's h_all stores
  {
    unsigned short* hb = h_all + ((size_t)(btile * 16 + cb) * Sn + tprev) * 768 + dir * Hn;
#pragma unroll
    for (int ph = 0; ph < 2; ++ph)
#pragma unroll
      for (int cc = 0; cc < 3; ++cc)
        hb[ph * 192 + cj * 3 + cc] = hprev[ph][cc];
  }
}

// ---------------------------------------------------------------------------
// out GEMM: A = h_all [32768][768] bf16, B = wlin [425][768] bf16
// out[m][n] fp32 = A@B^T + blin   (n predicated < 425)
__global__ void gemm_out(const unsigned short* __restrict__ A, const unsigned short* __restrict__ Bw,
                         const float* __restrict__ blin, float* __restrict__ out) {
  __shared__ __align__(16) unsigned short As[128 * 32];
  __shared__ __align__(16) unsigned short Bs[128 * 32];
  int tid = threadIdx.x, w = tid >> 6, l = tid & 63, lr = l & 15, lq = l >> 4;
  int mBase = blockIdx.x * 128, nBase = blockIdx.y * 128;
  int mw = (w & 1) * 64, nw = (w >> 1) * 64;
  f32x4 acc[4][4];
#pragma unroll
  for (int mt = 0; mt < 4; ++mt)
#pragma unroll
    for (int nt = 0; nt < 4; ++nt) acc[mt][nt] = (f32x4){0.f, 0.f, 0.f, 0.f};

  for (int kb = 0; kb < 24; ++kb) {
    int k0 = kb * 32;
#pragma unroll
    for (int j = 0; j < 2; ++j) {
      int g = j * 256 + tid;
      int row = g >> 2, kc = (g & 3) * 8;
      int nr = nBase + row; if (nr > Cn - 1) nr = Cn - 1;   // clamp: Wlin has 425 rows
      GLL16(A + (size_t)(mBase + row) * 768 + k0 + kc, (char*)As + (j * 256 + w * 64) * 16);
      GLL16(Bw + (size_t)nr * 768 + k0 + kc, (char*)Bs + (j * 256 + w * 64) * 16);
    }
    __syncthreads();
    short8 af[4], bfv[4];
#pragma unroll
    for (int mt = 0; mt < 4; ++mt) af[mt] = *(const short8*)&As[(mw + mt * 16 + lr) * 32 + lq * 8];
#pragma unroll
    for (int nt = 0; nt < 4; ++nt) bfv[nt] = *(const short8*)&Bs[(nw + nt * 16 + lr) * 32 + lq * 8];
#pragma unroll
    for (int mt = 0; mt < 4; ++mt)
#pragma unroll
      for (int nt = 0; nt < 4; ++nt)
        acc[mt][nt] = __builtin_amdgcn_mfma_f32_16x16x32_bf16(af[mt], bfv[nt], acc[mt][nt], 0, 0, 0);
    __syncthreads();
  }
#pragma unroll
  for (int nt = 0; nt < 4; ++nt) {
    int n = nBase + nw + nt * 16 + lr;
    if (n < Cn) {
      float bias = blin[n];
#pragma unroll
      for (int mt = 0; mt < 4; ++mt) {
        int mrow = mBase + mw + mt * 16 + lq * 4;
#pragma unroll
        for (int r = 0; r < 4; ++r) {
          int m = mrow + r;
          out[(size_t)m * Cn + n] = acc[mt][nt][r] + bias;
        }
      }
    }
  }
}

// ---------------------------------------------------------------------------
extern "C" void kernel_launch(void* const* d_in, const int* in_sizes, int n_in,
                              void* d_out, int out_size, void* d_ws, size_t ws_size,
                              hipStream_t stream) {
  (void)in_sizes; (void)n_in; (void)out_size;
  const float* f0     = (const float*)d_in[0];
  const int*   counts = (const int*)  d_in[1];
  const float* Wih_f  = (const float*)d_in[2];
  const float* Whh_f  = (const float*)d_in[3];
  const float* bih_f  = (const float*)d_in[4];
  const float* bhh_f  = (const float*)d_in[5];
  const float* Wih_b  = (const float*)d_in[6];
  const float* Whh_b  = (const float*)d_in[7];
  const float* bih_b  = (const float*)d_in[8];
  const float* bhh_b  = (const float*)d_in[9];
  const float* Wlin   = (const float*)d_in[10];
  const float* blin   = (const float*)d_in[11];
  float* out = (float*)d_out;

  char* ws = (char*)d_ws;
  size_t o = 0;
  auto alloc = [&](size_t bytes) { size_t cur = o; o += (bytes + 255) & ~(size_t)255; return cur; };
  size_t o_f0p    = alloc((size_t)Bn * Sn * Dn * 2);        // 50.3 MB (f0p; reused as h_all)
  size_t o_xp     = alloc((size_t)2 * Sn * Bn * G4H * 2);   // 201.3 MB
  size_t o_wih    = alloc((size_t)3072 * 768 * 2);
  size_t o_whh    = alloc((size_t)2 * 1536 * 384 * 2);
  size_t o_wlin   = alloc((size_t)Cn * 768 * 2);
  size_t o_bias   = alloc((size_t)3072 * 4);
  size_t o_starts = alloc((size_t)Bn * Wn * 4);
  if (o > ws_size) return;  // needs ~260 MiB of workspace

  unsigned short* f0p   = (unsigned short*)(ws + o_f0p);
  unsigned short* h_all = (unsigned short*)(ws + o_f0p);    // overlay: f0p dead after gemm_xp
  unsigned short* xp    = (unsigned short*)(ws + o_xp);
  unsigned short* wih   = (unsigned short*)(ws + o_wih);
  unsigned short* whh   = (unsigned short*)(ws + o_whh);
  unsigned short* wlin  = (unsigned short*)(ws + o_wlin);
  float*          biasc = (float*)(ws + o_bias);
  int*            starts= (int*)(ws + o_starts);

  scan_starts<<<Bn, 256, 0, stream>>>(counts, starts);
  {
    int total = 3072 * 768 + 2 * 1536 * 384 + Cn * 768 + 3072;
    prep_cast<<<(total + 255) / 256, 256, 0, stream>>>(Wih_f, Wih_b, Whh_f, Whh_b, Wlin,
                                                       bih_f, bhh_f, bih_b, bhh_b,
                                                       wih, whh, wlin, biasc);
  }
  pool_kernel<<<(Bn * Sn * 192) / 256, 256, 0, stream>>>(f0, counts, starts, f0p);
  gemm_xp<<<dim3(256, 24), 256, 0, stream>>>(f0p, wih, biasc, xp);
  recur_kernel<<<8, 1024, 0, stream>>>(whh, xp, h_all);
  gemm_out<<<dim3(256, 4), 256, 0, stream>>>(h_all, wlin, blin, out);
}

// Round 6
// 2087.646 us; speedup vs baseline: 8.7804x; 8.7804x over previous
//
#include <hip/hip_runtime.h>
#include <stdint.h>

// ---------------------------------------------------------------------------
// LSTMSupertaggingModel: segment-mean-pool -> BiLSTM(H=384) -> Linear(C=425)
// B=64, S=512, D=768, W=256, H=384, C=425
//
// R6 = R3 structure (48 wgs x 256: dir x 4 btile x 6 h-chunks, Whh slice
// register-resident) with the exchange critical path shortened:
//  - producer publishes tagged payload and NEVER waits (no end-of-step
//    barrier/vmcnt drain, no hint store);
//  - consumer wave 0 polls 24 SENTINEL payload words (one per producer wave,
//    that wave's last-issued word) -> one fabric hop less than hint scheme;
//  - payload then read once, deduped via LDS; tags remain ground truth with
//    per-wave retry (out-of-order store completion -> rare, brief).
//  - R5 lesson (structural): Whh per dir = 1.18 MB > 512 KB CU register
//    file -> single-CU recurrence impossible; cross-CU exchange is the game.
// ---------------------------------------------------------------------------

typedef __attribute__((ext_vector_type(8))) short short8;
typedef __attribute__((ext_vector_type(4))) float f32x4;

static constexpr int Bn = 64, Sn = 512, Dn = 768, Wn = 256, Hn = 384, Cn = 425;
static constexpr int G4H = 4 * Hn;          // 1536
static constexpr int NBT = 4;               // batch tiles of 16
static constexpr int NCK = 6;               // h-chunks of 64 rows per dir

__device__ __forceinline__ unsigned short f2bf(float f) {
  unsigned int u = __float_as_uint(f);
  u += 0x7FFFu + ((u >> 16) & 1u);          // round-to-nearest-even
  return (unsigned short)(u >> 16);
}
__device__ __forceinline__ float bf2f(unsigned short h) {
  return __uint_as_float(((unsigned int)h) << 16);
}
__device__ __forceinline__ float sigm(float x)  { return 1.f / (1.f + __expf(-x)); }
__device__ __forceinline__ float tanhft(float x){ return 1.f - 2.f / (__expf(2.f * x) + 1.f); }

// async global->LDS, 16B per lane; LDS dest = wave-uniform base + lane*16
#define GLL16(gp, lp) __builtin_amdgcn_global_load_lds( \
  (const __attribute__((address_space(1))) unsigned int*)(gp), \
  (__attribute__((address_space(3))) unsigned int*)(lp), 16, 0, 0)

// ---------------------------------------------------------------------------
// zero htag through the UC/atomic path (visibility to agent-scope atomics)
__global__ void zero_comm(unsigned int* p, int nwords) {
  int i = blockIdx.x * 256 + threadIdx.x;
  if (i < nwords)
    __hip_atomic_store(&p[i], 0u, __ATOMIC_RELAXED, __HIP_MEMORY_SCOPE_AGENT);
}

// ---------------------------------------------------------------------------
__global__ void scan_starts(const int* __restrict__ counts, int* __restrict__ starts) {
  int b = blockIdx.x, j = threadIdx.x;      // 64 blocks x 256 threads
  __shared__ int sm[256];
  int c = counts[b * Wn + j];
  sm[j] = c;
  __syncthreads();
  for (int off = 1; off < 256; off <<= 1) {
    int v = (j >= off) ? sm[j - off] : 0;
    __syncthreads();
    sm[j] += v;
    __syncthreads();
  }
  starts[b * Wn + j] = sm[j] - c;           // exclusive
}

// ---------------------------------------------------------------------------
__global__ void prep_cast(const float* __restrict__ Wih_f, const float* __restrict__ Wih_b,
                          const float* __restrict__ Whh_f, const float* __restrict__ Whh_b,
                          const float* __restrict__ Wlin,
                          const float* __restrict__ bih_f, const float* __restrict__ bhh_f,
                          const float* __restrict__ bih_b, const float* __restrict__ bhh_b,
                          unsigned short* __restrict__ wih, unsigned short* __restrict__ whh,
                          unsigned short* __restrict__ wlin, float* __restrict__ biasc) {
  int i = blockIdx.x * 256 + threadIdx.x;
  const int T0 = 3072 * 768;                // Wih both dirs
  const int T1 = 2 * 1536 * 384;            // Whh both dirs
  const int T2 = Cn * 768;                  // Wlin
  const int T3 = 3072;                      // bias
  if (i < T0) {
    int n = i / 768, k = i - n * 768;
    float v = (n < 1536) ? Wih_f[n * 768 + k] : Wih_b[(n - 1536) * 768 + k];
    wih[i] = f2bf(v);
  } else if (i < T0 + T1) {
    int j = i - T0;
    float v = (j < 1536 * 384) ? Whh_f[j] : Whh_b[j - 1536 * 384];
    whh[j] = f2bf(v);
  } else if (i < T0 + T1 + T2) {
    int j = i - T0 - T1;
    wlin[j] = f2bf(Wlin[j]);
  } else if (i < T0 + T1 + T2 + T3) {
    int n = i - T0 - T1 - T2;
    biasc[n] = (n < 1536) ? (bih_f[n] + bhh_f[n]) : (bih_b[n - 1536] + bhh_b[n - 1536]);
  }
}

// ---------------------------------------------------------------------------
// ragged segment mean: f0p[b*S+s][:] = s<W ? mean(f0[b, st..st+cnt)) : f0[b,s]
__global__ void pool_kernel(const float* __restrict__ f0, const int* __restrict__ counts,
                            const int* __restrict__ starts, unsigned short* __restrict__ f0p) {
  int idx = blockIdx.x * 256 + threadIdx.x;           // B*S*192 exact
  int dc = idx % 192;
  int rest = idx / 192;
  int s = rest & 511, b = rest >> 9;
  const float4* f4 = (const float4*)f0;
  float4 v;
  if (s < Wn) {
    int st = starts[b * Wn + s], cnt = counts[b * Wn + s];
    v = f4[(size_t)(b * Sn + st) * 192 + dc];
    if (cnt == 2) {
      float4 v2 = f4[(size_t)(b * Sn + st + 1) * 192 + dc];
      v.x = (v.x + v2.x) * 0.5f; v.y = (v.y + v2.y) * 0.5f;
      v.z = (v.z + v2.z) * 0.5f; v.w = (v.w + v2.w) * 0.5f;
    }
  } else {
    v = f4[(size_t)(b * Sn + s) * 192 + dc];
  }
  ushort4 o;
  o.x = f2bf(v.x); o.y = f2bf(v.y); o.z = f2bf(v.z); o.w = f2bf(v.w);
  ((ushort4*)f0p)[(size_t)(b * Sn + s) * 192 + dc] = o;
}

// ---------------------------------------------------------------------------
// xp GEMM: A = f0p [32768][768] bf16, B = wih [3072][768] bf16 (rows = gate)
// out: xp[d][t][b][1536] bf16,  value = A@B^T + biasc
__global__ void gemm_xp(const unsigned short* __restrict__ A, const unsigned short* __restrict__ Bw,
                        const float* __restrict__ biasc, unsigned short* __restrict__ xp) {
  __shared__ __align__(16) unsigned short As[128 * 32];
  __shared__ __align__(16) unsigned short Bs[128 * 32];
  int tid = threadIdx.x, w = tid >> 6, l = tid & 63, lr = l & 15, lq = l >> 4;
  int mBase = blockIdx.x * 128, nBase = blockIdx.y * 128;
  int mw = (w & 1) * 64, nw = (w >> 1) * 64;
  f32x4 acc[4][4];
#pragma unroll
  for (int mt = 0; mt < 4; ++mt)
#pragma unroll
    for (int nt = 0; nt < 4; ++nt) acc[mt][nt] = (f32x4){0.f, 0.f, 0.f, 0.f};

  for (int kb = 0; kb < 24; ++kb) {
    int k0 = kb * 32;
#pragma unroll
    for (int j = 0; j < 2; ++j) {
      int g = j * 256 + tid;
      int row = g >> 2, kc = (g & 3) * 8;
      GLL16(A + (size_t)(mBase + row) * 768 + k0 + kc, (char*)As + (j * 256 + w * 64) * 16);
      GLL16(Bw + (size_t)(nBase + row) * 768 + k0 + kc, (char*)Bs + (j * 256 + w * 64) * 16);
    }
    __syncthreads();
    short8 af[4], bfv[4];
#pragma unroll
    for (int mt = 0; mt < 4; ++mt) af[mt] = *(const short8*)&As[(mw + mt * 16 + lr) * 32 + lq * 8];
#pragma unroll
    for (int nt = 0; nt < 4; ++nt) bfv[nt] = *(const short8*)&Bs[(nw + nt * 16 + lr) * 32 + lq * 8];
#pragma unroll
    for (int mt = 0; mt < 4; ++mt)
#pragma unroll
      for (int nt = 0; nt < 4; ++nt)
        acc[mt][nt] = __builtin_amdgcn_mfma_f32_16x16x32_bf16(af[mt], bfv[nt], acc[mt][nt], 0, 0, 0);
    __syncthreads();
  }
  // epilogue: +bias, scatter to xp[d][t][b][g]
#pragma unroll
  for (int nt = 0; nt < 4; ++nt) {
    int n = nBase + nw + nt * 16 + lr;
    float bias = biasc[n];
    int d = (n >= 1536) ? 1 : 0;
    int gI = n - d * 1536;
#pragma unroll
    for (int mt = 0; mt < 4; ++mt) {
      int mrow = mBase + mw + mt * 16 + lq * 4;
#pragma unroll
      for (int r = 0; r < 4; ++r) {
        int m = mrow + r;
        int t = m & 511, b = m >> 9;
        xp[((size_t)((d * Sn + t) * Bn + b)) * 1536 + gI] = f2bf(acc[mt][nt][r] + bias);
      }
    }
  }
}

// ---------------------------------------------------------------------------
// Recurrence. wg = (dir, btile, chunk); wave w owns h-rows chunk*64+w*16..+16,
// batch rows btile*16..+16, all 4 gates (cell fully lane-local).
// htag[dir][slot][64][384] u32 = (tag<<16)|bf16, tag = producer_step+1.
// Sentinel for producer wave (c,w'): word (b=btile*16+15, h=c*64+w'*16+15) —
// that wave's last-issued store. Poll sentinels, then read payload once.
__global__ void __launch_bounds__(256, 1)
recur_kernel(const unsigned short* __restrict__ whh,   // [2][1536][384] bf16
             const unsigned short* __restrict__ xp,    // [2][512][64][1536] bf16
             unsigned short* __restrict__ h_all,       // [64][512][768] bf16
             unsigned int* __restrict__ htag) {        // [2][2][64][384] u32
  int bid = blockIdx.x;
  int dir = bid / (NBT * NCK);
  int rem = bid % (NBT * NCK);
  int btile = rem / NCK, chunk = rem % NCK;
  int tid = threadIdx.x, w = tid >> 6, l = tid & 63, lr = l & 15, lq = l >> 4;
  int hwb = chunk * 64 + w * 16;            // wave's h-row base (within dir)
  int pr = tid >> 4, pk = tid & 15;         // payload: row 0..15, lane-in-row 0..15

  __shared__ unsigned int hlds[16 * 196];   // 12.5 KB; single buffer (barriers A/B)

  // permanent B-frags: whh[dir][q*384 + hwb + lr][kf*32 + lq*8 .. +8]
  short8 bfr[4][12];
#pragma unroll
  for (int q = 0; q < 4; ++q)
#pragma unroll
    for (int kf = 0; kf < 12; ++kf)
      bfr[q][kf] = *(const short8*)&whh[((size_t)dir * 1536 + q * 384 + hwb + lr) * 384 + kf * 32 + lq * 8];

  f32x4 c0 = (f32x4){0.f, 0.f, 0.f, 0.f};

  for (int it = 0; it < Sn; ++it) {
    int t = dir ? (Sn - 1 - it) : it;

    // gate init from xp (plain loads; issued before any waiting)
    f32x4 acc[4];
#pragma unroll
    for (int q = 0; q < 4; ++q) {
#pragma unroll
      for (int r = 0; r < 4; ++r) {
        int b = btile * 16 + lq * 4 + r;
        acc[q][r] = bf2f(xp[((size_t)((dir * Sn + t) * Bn + b)) * 1536 + q * 384 + hwb + lr]);
      }
    }

    if (it > 0) {
      const unsigned int expT = (unsigned int)it;
      int slot = (it - 1) & 1;
      const unsigned int* tbase = htag + (size_t)(dir * 2 + slot) * 64 * 384;
      // 1) sentinel poll: wave 0 watches 24 payload words (1 per producer wave)
      if (w == 0) {
        int li = (l < 24) ? l : 0;
        int c = li >> 2, w2 = li & 3;
        const unsigned int* sp = tbase + (size_t)(btile * 16 + 15) * 384 + c * 64 + w2 * 16 + 15;
        int got = (l < 24) ? 0 : 1;
        while (true) {
          if (!got)
            got = ((__hip_atomic_load(sp, __ATOMIC_RELAXED, __HIP_MEMORY_SCOPE_AGENT) >> 16) >= expT) ? 1 : 0;
          if (__all(got)) break;
          __builtin_amdgcn_s_sleep(1);
        }
      }
      __syncthreads();                      // barrier A (also isolates hlds reuse)
      // 2) payload read ONCE, deduped across waves; tags = ground truth
      const unsigned long long* srow = (const unsigned long long*)
          (tbase + (size_t)(btile * 16 + pr) * 384);
      unsigned long long v[12];
      bool ok;
      do {
        ok = true;
#pragma unroll
        for (int i = 0; i < 12; ++i) {
          unsigned long long x = __hip_atomic_load(&srow[pk + 16 * i],
                                   __ATOMIC_RELAXED, __HIP_MEMORY_SCOPE_AGENT);
          v[i] = x;
          ok &= (((unsigned int)(x >> 16) & 0xffffu) == expT) &
                ((unsigned int)(x >> 48) == expT);
        }
        if (__all((int)ok)) break;
        __builtin_amdgcn_s_sleep(1);        // rare: stores landed out of order
      } while (true);
#pragma unroll
      for (int i = 0; i < 12; ++i)
        hlds[pr * 196 + pk + 16 * i] = ((unsigned int)v[i] & 0xffffu) |
                                       (((unsigned int)(v[i] >> 32) & 0xffffu) << 16);
      __syncthreads();                      // barrier B: hlds filled wg-wide
      // 3) A-frags from LDS, MFMA over 12 k-tiles x 4 gates
#pragma unroll
      for (int kf = 0; kf < 12; ++kf) {
        short8 a = *(const short8*)((const char*)hlds + lr * 784 + kf * 64 + lq * 16);
#pragma unroll
        for (int q = 0; q < 4; ++q)
          acc[q] = __builtin_amdgcn_mfma_f32_16x16x32_bf16(a, bfr[q][kf], acc[q], 0, 0, 0);
      }
    }

    // elementwise LSTM cell + publish (producer NEVER waits)
    unsigned int outTag = (unsigned int)(it + 1) << 16;
    int oslot = it & 1;
    unsigned int* obase = htag + (size_t)(dir * 2 + oslot) * 64 * 384;
    unsigned short hb16v[4];
#pragma unroll
    for (int r = 0; r < 4; ++r) {
      float iv = sigm(acc[0][r]);
      float fv = sigm(acc[1][r]);
      float gv = tanhft(acc[2][r]);
      float ov = sigm(acc[3][r]);
      float cf = fv * c0[r] + iv * gv;
      c0[r] = cf;
      float hv = ov * tanhft(cf);
      hb16v[r] = f2bf(hv);
      int b = btile * 16 + lq * 4 + r;
      __hip_atomic_store(&obase[(size_t)b * 384 + hwb + lr],
                         outTag | hb16v[r], __ATOMIC_RELAXED, __HIP_MEMORY_SCOPE_AGENT);
    }
#pragma unroll
    for (int r = 0; r < 4; ++r) {           // plain copy for gemm_out (after publish)
      int b = btile * 16 + lq * 4 + r;
      h_all[((size_t)b * Sn + t) * 768 + dir * Hn + hwb + lr] = hb16v[r];
    }
  }
}

// ---------------------------------------------------------------------------
// out GEMM: A = h_all [32768][768] bf16, B = wlin [425][768] bf16
// out[m][n] fp32 = A@B^T + blin   (n predicated < 425)
__global__ void gemm_out(const unsigned short* __restrict__ A, const unsigned short* __restrict__ Bw,
                         const float* __restrict__ blin, float* __restrict__ out) {
  __shared__ __align__(16) unsigned short As[128 * 32];
  __shared__ __align__(16) unsigned short Bs[128 * 32];
  int tid = threadIdx.x, w = tid >> 6, l = tid & 63, lr = l & 15, lq = l >> 4;
  int mBase = blockIdx.x * 128, nBase = blockIdx.y * 128;
  int mw = (w & 1) * 64, nw = (w >> 1) * 64;
  f32x4 acc[4][4];
#pragma unroll
  for (int mt = 0; mt < 4; ++mt)
#pragma unroll
    for (int nt = 0; nt < 4; ++nt) acc[mt][nt] = (f32x4){0.f, 0.f, 0.f, 0.f};

  for (int kb = 0; kb < 24; ++kb) {
    int k0 = kb * 32;
#pragma unroll
    for (int j = 0; j < 2; ++j) {
      int g = j * 256 + tid;
      int row = g >> 2, kc = (g & 3) * 8;
      int nr = nBase + row; if (nr > Cn - 1) nr = Cn - 1;   // clamp: Wlin has 425 rows
      GLL16(A + (size_t)(mBase + row) * 768 + k0 + kc, (char*)As + (j * 256 + w * 64) * 16);
      GLL16(Bw + (size_t)nr * 768 + k0 + kc, (char*)Bs + (j * 256 + w * 64) * 16);
    }
    __syncthreads();
    short8 af[4], bfv[4];
#pragma unroll
    for (int mt = 0; mt < 4; ++mt) af[mt] = *(const short8*)&As[(mw + mt * 16 + lr) * 32 + lq * 8];
#pragma unroll
    for (int nt = 0; nt < 4; ++nt) bfv[nt] = *(const short8*)&Bs[(nw + nt * 16 + lr) * 32 + lq * 8];
#pragma unroll
    for (int mt = 0; mt < 4; ++mt)
#pragma unroll
      for (int nt = 0; nt < 4; ++nt)
        acc[mt][nt] = __builtin_amdgcn_mfma_f32_16x16x32_bf16(af[mt], bfv[nt], acc[mt][nt], 0, 0, 0);
    __syncthreads();
  }
#pragma unroll
  for (int nt = 0; nt < 4; ++nt) {
    int n = nBase + nw + nt * 16 + lr;
    if (n < Cn) {
      float bias = blin[n];
#pragma unroll
      for (int mt = 0; mt < 4; ++mt) {
        int mrow = mBase + mw + mt * 16 + lq * 4;
#pragma unroll
        for (int r = 0; r < 4; ++r) {
          int m = mrow + r;
          out[(size_t)m * Cn + n] = acc[mt][nt][r] + bias;
        }
      }
    }
  }
}

// ---------------------------------------------------------------------------
extern "C" void kernel_launch(void* const* d_in, const int* in_sizes, int n_in,
                              void* d_out, int out_size, void* d_ws, size_t ws_size,
                              hipStream_t stream) {
  (void)in_sizes; (void)n_in; (void)out_size;
  const float* f0     = (const float*)d_in[0];
  const int*   counts = (const int*)  d_in[1];
  const float* Wih_f  = (const float*)d_in[2];
  const float* Whh_f  = (const float*)d_in[3];
  const float* bih_f  = (const float*)d_in[4];
  const float* bhh_f  = (const float*)d_in[5];
  const float* Wih_b  = (const float*)d_in[6];
  const float* Whh_b  = (const float*)d_in[7];
  const float* bih_b  = (const float*)d_in[8];
  const float* bhh_b  = (const float*)d_in[9];
  const float* Wlin   = (const float*)d_in[10];
  const float* blin   = (const float*)d_in[11];
  float* out = (float*)d_out;

  char* ws = (char*)d_ws;
  size_t o = 0;
  auto alloc = [&](size_t bytes) { size_t cur = o; o += (bytes + 255) & ~(size_t)255; return cur; };
  size_t o_f0p    = alloc((size_t)Bn * Sn * Dn * 2);        // 50.3 MB (f0p; reused as h_all)
  size_t o_xp     = alloc((size_t)2 * Sn * Bn * G4H * 2);   // 201.3 MB
  size_t o_wih    = alloc((size_t)3072 * 768 * 2);
  size_t o_whh    = alloc((size_t)2 * 1536 * 384 * 2);
  size_t o_wlin   = alloc((size_t)Cn * 768 * 2);
  size_t o_bias   = alloc((size_t)3072 * 4);
  size_t o_starts = alloc((size_t)Bn * Wn * 4);
  size_t o_htag   = alloc((size_t)2 * 2 * 64 * 384 * 4);    // 786 KB
  if (o > ws_size) return;  // needs ~261 MiB of workspace

  unsigned short* f0p   = (unsigned short*)(ws + o_f0p);
  unsigned short* h_all = (unsigned short*)(ws + o_f0p);    // overlay: f0p dead after gemm_xp
  unsigned short* xp    = (unsigned short*)(ws + o_xp);
  unsigned short* wih   = (unsigned short*)(ws + o_wih);
  unsigned short* whh   = (unsigned short*)(ws + o_whh);
  unsigned short* wlin  = (unsigned short*)(ws + o_wlin);
  float*          biasc = (float*)(ws + o_bias);
  int*            starts= (int*)(ws + o_starts);
  unsigned int*   htag  = (unsigned int*)(ws + o_htag);

  {
    int nwords = 2 * 2 * 64 * 384;                          // htag
    zero_comm<<<(nwords + 255) / 256, 256, 0, stream>>>(htag, nwords);
  }
  scan_starts<<<Bn, 256, 0, stream>>>(counts, starts);
  {
    int total = 3072 * 768 + 2 * 1536 * 384 + Cn * 768 + 3072;
    prep_cast<<<(total + 255) / 256, 256, 0, stream>>>(Wih_f, Wih_b, Whh_f, Whh_b, Wlin,
                                                       bih_f, bhh_f, bih_b, bhh_b,
                                                       wih, whh, wlin, biasc);
  }
  pool_kernel<<<(Bn * Sn * 192) / 256, 256, 0, stream>>>(f0, counts, starts, f0p);
  gemm_xp<<<dim3(256, 24), 256, 0, stream>>>(f0p, wih, biasc, xp);
  recur_kernel<<<2 * NBT * NCK, 256, 0, stream>>>(whh, xp, h_all, htag);
  gemm_out<<<dim3(256, 4), 256, 0, stream>>>(h_all, wlin, blin, out);
}